// Round 12
// baseline (344.236 us; speedup 1.0000x reference)
//
#include <hip/hip_runtime.h>

// sparsemax over axis=2 of x[8][16][4096][64] (fp32) — 4 passes, single x-sweep
// for stats.
//
// R11 evidence: 5-pass total ≈126us GPU (dur 281 - ~155us harness resets; our
// kernels all below the 512MB ws-poison fills that own the top-5 at 6.8 TB/s).
// R12: p2's full L3 pass is replaced by a 64KB block-local re-read inside p1:
//   threshold chunkmax-1 <= gmax-1  =>  candidate superset; extras have
//   z = v-gmax <= -1 <= tau and are inert in Newton (absmax 0.0 since R6).
// Candidates/col ~= 198 avg -> single per-col list, cap 384; overflow ->
// strided-column fallback (prob ~0, correct).
//
// p0: gcnt = 0 (tiny).
// p1: per-(slab, 256-row chunk): loop A max (HBM read, contiguous f4/thread);
//     chunk max -> pmax[col][chunk] (no atomics); loop B re-read own 64KB
//     (L2-hot) extract v > chunkmax-1 -> glist[col][<=384] atomic append.
// p3: per col (1 wave): gmax = max(16 partials via lane-parallel load + xor
//     reduce); Newton-from-below on z = v-gmax over the list (exact,
//     piecewise-linear, bitwise fixed-point stop); writes gmax, tau.
// p4: R7-proven grid-stride apply: out = relu((x-gmax)-tau).
//
// ws (~13.2 MB): pmax f[8192*16] | gcnt i[8192] | glist f[8192*384]
//                | gmax f[8192] | tau f[8192]. Too small -> fused fallback.

#define PCAP 384

typedef float f32x4 __attribute__((ext_vector_type(4)));

// ---------------------------------------------------------------- P0 ----
__global__ __launch_bounds__(256)
void p0_init(int* __restrict__ gcnt, int ncols)
{
    int i = blockIdx.x * 256 + threadIdx.x;
    if (i < ncols) gcnt[i] = 0;
}

// ---------------------------------------------------------------- P1 ----
// block=(slab, rb): 256 contiguous rows x 64 cols = 64KB.
__global__ __launch_bounds__(256)
void p1_maxextract(const float* __restrict__ x,
                   float* __restrict__ pmax,    // [ncols][16]
                   int*   __restrict__ gcnt,    // [ncols]
                   float* __restrict__ glist)   // [ncols][PCAP]
{
    const int b    = blockIdx.x;        // 0..2047
    const int slab = b >> 4;
    const int rb   = b & 15;
    const int t    = threadIdx.x;       // 0..255
    const int l    = t & 63;
    const int wv   = t >> 6;            // 0..3
    const int d4   = t & 15;

    __shared__ float red[4][64];
    __shared__ float bmax[64];

    const f32x4* __restrict__ x4 = reinterpret_cast<const f32x4*>(x);
    const size_t base = (size_t)slab * 65536 + (size_t)rb * 4096;

    // ---- loop A: chunk max (HBM read; 1 f4/thread/iter, proven shape) ----
    f32x4 m;
    m.x = m.y = m.z = m.w = -__builtin_huge_valf();
    for (int k = 0; k < 16; ++k) {
        f32x4 v = x4[base + (size_t)k * 256 + t];
        m.x = fmaxf(m.x, v.x);
        m.y = fmaxf(m.y, v.y);
        m.z = fmaxf(m.z, v.z);
        m.w = fmaxf(m.w, v.w);
    }
#pragma unroll
    for (int mask = 16; mask <= 32; mask <<= 1) {   // keeps d4 class
        m.x = fmaxf(m.x, __shfl_xor(m.x, mask));
        m.y = fmaxf(m.y, __shfl_xor(m.y, mask));
        m.z = fmaxf(m.z, __shfl_xor(m.z, mask));
        m.w = fmaxf(m.w, __shfl_xor(m.w, mask));
    }
    if (l < 16) {
        red[wv][l * 4 + 0] = m.x;
        red[wv][l * 4 + 1] = m.y;
        red[wv][l * 4 + 2] = m.z;
        red[wv][l * 4 + 3] = m.w;
    }
    __syncthreads();
    if (t < 64) {
        float g = fmaxf(fmaxf(red[0][t], red[1][t]), fmaxf(red[2][t], red[3][t]));
        bmax[t] = g;
        pmax[((size_t)slab * 64 + t) * 16 + rb] = g;   // no atomics
    }
    __syncthreads();

    // ---- loop B: re-read own 64KB (L2-hot), extract with chunkmax-1 ----
    const int  c0 = d4 << 2;
    const int  colbase = slab * 64 + c0;
    const float T0 = bmax[c0 + 0] - 1.0f;
    const float T1 = bmax[c0 + 1] - 1.0f;
    const float T2 = bmax[c0 + 2] - 1.0f;
    const float T3 = bmax[c0 + 3] - 1.0f;

    for (int k = 0; k < 16; ++k) {
        f32x4 v = x4[base + (size_t)k * 256 + t];
        if (v.x > T0) { int i = atomicAdd(&gcnt[colbase+0], 1); if (i < PCAP) glist[(size_t)(colbase+0)*PCAP + i] = v.x; }
        if (v.y > T1) { int i = atomicAdd(&gcnt[colbase+1], 1); if (i < PCAP) glist[(size_t)(colbase+1)*PCAP + i] = v.y; }
        if (v.z > T2) { int i = atomicAdd(&gcnt[colbase+2], 1); if (i < PCAP) glist[(size_t)(colbase+2)*PCAP + i] = v.z; }
        if (v.w > T3) { int i = atomicAdd(&gcnt[colbase+3], 1); if (i < PCAP) glist[(size_t)(colbase+3)*PCAP + i] = v.w; }
    }
}

// ---------------------------------------------------------------- P3 ----
__global__ __launch_bounds__(1024)
void p3_newton(const float* __restrict__ x,
               const float* __restrict__ pmax,
               const int*   __restrict__ gcnt,
               const float* __restrict__ glist,
               float* __restrict__ gmaxo,
               float* __restrict__ tauo)
{
    const int col = blockIdx.x * 16 + (threadIdx.x >> 6);  // 0..8191
    const int l   = threadIdx.x & 63;

    // gmax = max of 16 chunk partials: lanes load partial (l&15), xor-reduce 1..8
    float g = pmax[(size_t)col * 16 + (l & 15)];
#pragma unroll
    for (int mask = 1; mask <= 8; mask <<= 1)
        g = fmaxf(g, __shfl_xor(g, mask));
    // every 16-lane group now holds the same full max; all 64 lanes agree

    const int n = gcnt[col];
    float tau = -1.0f;
    if (n <= PCAP) {
        const float* __restrict__ L = glist + (size_t)col * PCAP;
        for (int it = 0; it < 64; ++it) {
            float sv = 0.f, cn = 0.f;
            for (int p = l; p < n; p += 64) {
                float z = L[p] - g;                 // reference rounding (x - max)
                if (z > tau) { sv += z; cn += 1.f; }
            }
#pragma unroll
            for (int mask = 1; mask <= 32; mask <<= 1) {
                sv += __shfl_xor(sv, mask);
                cn += __shfl_xor(cn, mask);
            }
            if (cn < 0.5f) break;
            float tn = (sv - 1.0f) / cn;
            tn = fmaxf(tn, tau);                    // monotone ascent from below
            if (tn == tau) break;                   // exact fixed point
            tau = tn;
        }
    } else {
        // correctness fallback (P ~ 0): strided full-column read
        const int slab = col >> 6, d = col & 63;
        const float* vb = x + (size_t)slab * 262144 + d;
        for (int it = 0; it < 64; ++it) {
            float sv = 0.f, cn = 0.f;
            for (int p = l; p < 4096; p += 64) {
                float z = vb[(size_t)p * 64] - g;
                if (z > tau) { sv += z; cn += 1.f; }
            }
#pragma unroll
            for (int mask = 1; mask <= 32; mask <<= 1) {
                sv += __shfl_xor(sv, mask);
                cn += __shfl_xor(cn, mask);
            }
            if (cn < 0.5f) break;
            float tn = (sv - 1.0f) / cn;
            tn = fmaxf(tn, tau);
            if (tn == tau) break;
            tau = tn;
        }
    }
    if (l == 0) { gmaxo[col] = g; tauo[col] = tau; }
}

// ---------------------------------------------------------------- P4 ----
// verbatim R7/R11 apply shape (measured fast).
__global__ __launch_bounds__(256)
void p4_apply(const float* __restrict__ x,
              const float* __restrict__ gmax_in,
              const float* __restrict__ tau_in,
              float* __restrict__ out, int n4)
{
    const f32x4* __restrict__ x4 = reinterpret_cast<const f32x4*>(x);
    const f32x4* __restrict__ g4 = reinterpret_cast<const f32x4*>(gmax_in);
    const f32x4* __restrict__ t4 = reinterpret_cast<const f32x4*>(tau_in);
    f32x4* __restrict__ o4       = reinterpret_cast<f32x4*>(out);

    const int stride = gridDim.x * 256;
    for (int f = blockIdx.x * 256 + threadIdx.x; f < n4; f += stride) {
        const int d4 = f & 15;
        const int bh = f >> 16;
        const int v  = bh * 16 + d4;
        f32x4 xv = x4[f];
        f32x4 g  = g4[v];
        f32x4 tv = t4[v];
        f32x4 o;
        o.x = fmaxf((xv.x - g.x) - tv.x, 0.f);
        o.y = fmaxf((xv.y - g.y) - tv.y, 0.f);
        o.z = fmaxf((xv.z - g.z) - tv.z, 0.f);
        o.w = fmaxf((xv.w - g.w) - tv.w, 0.f);
        o4[f] = o;
    }
}

// ------------------------------------------- fallback: fused (known-good) ----
#define C_CAP 256
__global__ __launch_bounds__(1024, 4)
void sparsemax_fused(const float* __restrict__ x, float* __restrict__ out)
{
    const int b = blockIdx.x, bh = b >> 2, dt = b & 3;
    const int t = threadIdx.x, lane = t & 63, wv = t >> 6, dq = t & 3, iblk = t >> 2;
    __shared__ float list[16][C_CAP];
    __shared__ float redbuf[256];
    __shared__ float gmaxT[16];
    __shared__ float tauLDS[16];
    __shared__ int   cnt[16];
    const f32x4* __restrict__ x4 = reinterpret_cast<const f32x4*>(x);
    f32x4* __restrict__ o4       = reinterpret_cast<f32x4*>(out);
    const size_t slabrow = (size_t)bh * 4096;
    const size_t idx0 = (slabrow + (size_t)iblk) * 16 + (size_t)(dt * 4) + (size_t)dq;
    f32x4 c[16];
#pragma unroll
    for (int s = 0; s < 16; ++s) c[s] = x4[idx0 + (size_t)s * 4096];
    f32x4 m = c[0];
#pragma unroll
    for (int s = 1; s < 16; ++s) {
        m.x = fmaxf(m.x, c[s].x); m.y = fmaxf(m.y, c[s].y);
        m.z = fmaxf(m.z, c[s].z); m.w = fmaxf(m.w, c[s].w);
    }
#pragma unroll
    for (int mask = 4; mask <= 32; mask <<= 1) {
        m.x = fmaxf(m.x, __shfl_xor(m.x, mask));
        m.y = fmaxf(m.y, __shfl_xor(m.y, mask));
        m.z = fmaxf(m.z, __shfl_xor(m.z, mask));
        m.w = fmaxf(m.w, __shfl_xor(m.w, mask));
    }
    if (lane < 4) {
        redbuf[wv*16 + lane*4 + 0] = m.x; redbuf[wv*16 + lane*4 + 1] = m.y;
        redbuf[wv*16 + lane*4 + 2] = m.z; redbuf[wv*16 + lane*4 + 3] = m.w;
    }
    __syncthreads();
    if (t < 16) {
        float g = redbuf[t];
#pragma unroll
        for (int w = 1; w < 16; ++w) g = fmaxf(g, redbuf[w*16 + t]);
        gmaxT[t] = g; cnt[t] = 0;
    }
    __syncthreads();
    const int j0 = dq << 2;
    f32x4 g4v;
    g4v.x = gmaxT[j0+0]; g4v.y = gmaxT[j0+1]; g4v.z = gmaxT[j0+2]; g4v.w = gmaxT[j0+3];
#pragma unroll
    for (int s = 0; s < 16; ++s) {
        float zx = c[s].x - g4v.x, zy = c[s].y - g4v.y, zz = c[s].z - g4v.z, zw = c[s].w - g4v.w;
        if (zx > -1.0f) { int p = atomicAdd(&cnt[j0+0],1); if (p < C_CAP) list[j0+0][p] = zx; }
        if (zy > -1.0f) { int p = atomicAdd(&cnt[j0+1],1); if (p < C_CAP) list[j0+1][p] = zy; }
        if (zz > -1.0f) { int p = atomicAdd(&cnt[j0+2],1); if (p < C_CAP) list[j0+2][p] = zz; }
        if (zw > -1.0f) { int p = atomicAdd(&cnt[j0+3],1); if (p < C_CAP) list[j0+3][p] = zw; }
    }
    __syncthreads();
    {
        const int j = wv; const int n = cnt[j]; float tau = -1.0f;
        if (n <= C_CAP) {
            for (int it = 0; it < 100; ++it) {
                float sv = 0.f, cc = 0.f;
                for (int p = lane; p < n; p += 64) {
                    float v = list[j][p];
                    if (v > tau) { sv += v; cc += 1.f; }
                }
#pragma unroll
                for (int mask = 1; mask <= 32; mask <<= 1) { sv += __shfl_xor(sv, mask); cc += __shfl_xor(cc, mask); }
                if (cc < 0.5f) break;
                float tn = (sv - 1.0f) / cc; tn = fmaxf(tn, tau);
                if (tn == tau) break; tau = tn;
            }
        } else {
            const float g = gmaxT[j];
            const float* vb = x + slabrow * 64 + (size_t)(dt * 16 + j);
            for (int it = 0; it < 100; ++it) {
                float sv = 0.f, cc = 0.f;
                for (int p = lane; p < 4096; p += 64) {
                    float v = vb[(size_t)p * 64] - g;
                    if (v > tau) { sv += v; cc += 1.f; }
                }
#pragma unroll
                for (int mask = 1; mask <= 32; mask <<= 1) { sv += __shfl_xor(sv, mask); cc += __shfl_xor(cc, mask); }
                if (cc < 0.5f) break;
                float tn = (sv - 1.0f) / cc; tn = fmaxf(tn, tau);
                if (tn == tau) break; tau = tn;
            }
        }
        if (lane == 0) tauLDS[j] = tau;
    }
    __syncthreads();
    f32x4 tau4;
    tau4.x = tauLDS[j0+0]; tau4.y = tauLDS[j0+1]; tau4.z = tauLDS[j0+2]; tau4.w = tauLDS[j0+3];
#pragma unroll
    for (int s = 0; s < 16; ++s) {
        f32x4 o;
        o.x = fmaxf((c[s].x - g4v.x) - tau4.x, 0.f);
        o.y = fmaxf((c[s].y - g4v.y) - tau4.y, 0.f);
        o.z = fmaxf((c[s].z - g4v.z) - tau4.z, 0.f);
        o.w = fmaxf((c[s].w - g4v.w) - tau4.w, 0.f);
        o4[idx0 + (size_t)s * 4096] = o;
    }
}

extern "C" void kernel_launch(void* const* d_in, const int* in_sizes, int n_in,
                              void* d_out, int out_size, void* d_ws, size_t ws_size,
                              hipStream_t stream)
{
    (void)n_in; (void)out_size;
    const float* x = (const float*)d_in[0];
    float* out     = (float*)d_out;
    const int total = in_sizes[0];            // 33554432
    const int slabs = total / (4096 * 64);    // 128
    const int ncols = slabs * 64;             // 8192
    const int n4    = total / 4;

    const size_t off_pmax  = 0;                                   // f[ncols*16]
    const size_t off_gcnt  = off_pmax + (size_t)ncols * 16 * 4;   // i[ncols]
    const size_t off_glist = off_gcnt + (size_t)ncols * 4;        // f[ncols*PCAP]
    const size_t off_gmax  = off_glist + (size_t)ncols * PCAP * 4;
    const size_t off_tau   = off_gmax + (size_t)ncols * 4;
    const size_t ws_need   = off_tau + (size_t)ncols * 4;

    if (ws_size < ws_need) {
        hipLaunchKernelGGL(sparsemax_fused, dim3(slabs * 4), dim3(1024), 0, stream, x, out);
        return;
    }

    char* ws = (char*)d_ws;
    float* pmax  = (float*)(ws + off_pmax);
    int*   gcnt  = (int*)  (ws + off_gcnt);
    float* glist = (float*)(ws + off_glist);
    float* gmax  = (float*)(ws + off_gmax);
    float* tau   = (float*)(ws + off_tau);

    hipLaunchKernelGGL(p0_init,       dim3((ncols + 255) / 256), dim3(256), 0, stream, gcnt, ncols);
    hipLaunchKernelGGL(p1_maxextract, dim3(slabs * 16), dim3(256), 0, stream, x, pmax, gcnt, glist);
    hipLaunchKernelGGL(p3_newton,     dim3(ncols / 16), dim3(1024), 0, stream, x, pmax, gcnt, glist, gmax, tau);
    hipLaunchKernelGGL(p4_apply,      dim3(2048), dim3(256), 0, stream, x, gmax, tau, out, n4);
}